// Round 1
// baseline (1930.310 us; speedup 1.0000x reference)
//
#include <hip/hip_runtime.h>
#include <hip/hip_bf16.h>

#define NR 30000
#define NU 70000
#define RE 8
#define HD 128
#define NE 1000000
#define NBINS ((NU + NR) * RE)      // 800000 bins: [user*8+t | 560000 + repo*8+t]
#define L2BASE (NU * RE)            // 560000
#define NSCAN ((NBINS + 1023) / 1024) // 782

// ---------------- MLP: h_repo = relu(x @ mlp_w + mlp_b), repos only ----------------
__global__ void k_mlp(const float* __restrict__ x, const float* __restrict__ mw,
                      const float* __restrict__ mb, float* __restrict__ h) {
  int gid = blockIdx.x * blockDim.x + threadIdx.x;
  if (gid >= NR * HD) return;
  int j = gid >> 7, o = gid & 127;
  float acc = mb[o];
  const float* xr = x + j * 8;
#pragma unroll
  for (int i = 0; i < 8; i++) acc += xr[i] * mw[i * HD + o];
  h[gid] = fmaxf(acc, 0.f);
}

// ---------------- c1 = relu(mlp_b) @ root1 + b1 (layer-1 root term for ALL users) ----
__global__ void k_c1(const float* __restrict__ mb, const float* __restrict__ root1,
                     const float* __restrict__ b1, float* __restrict__ c1) {
  __shared__ float hu[HD];
  int t = threadIdx.x;
  hu[t] = fmaxf(mb[t], 0.f);
  __syncthreads();
  float acc = b1[t];
  for (int h = 0; h < HD; ++h) acc += hu[h] * root1[h * HD + t];
  c1[t] = acc;
}

// ---------------- CSR build: histogram -> scan -> scatter ----------------
__global__ void k_hist(const int* __restrict__ er, const int* __restrict__ ea,
                       const int* __restrict__ et, unsigned* __restrict__ cnt) {
  int e = blockIdx.x * blockDim.x + threadIdx.x;
  if (e >= NE) return;
  int a = ea[e], t = et[e], p = er[e];
  atomicAdd(&cnt[a * RE + t], 1u);
  atomicAdd(&cnt[L2BASE + p * RE + t], 1u);
}

__global__ void k_scan1(const unsigned* __restrict__ cnt, unsigned* __restrict__ off,
                        unsigned* __restrict__ aux) {
  __shared__ unsigned s[256];
  int tid = threadIdx.x;
  int base = blockIdx.x * 1024 + tid * 4;
  unsigned v[4];
#pragma unroll
  for (int i = 0; i < 4; i++) v[i] = (base + i < NBINS) ? cnt[base + i] : 0u;
  unsigned tsum = v[0] + v[1] + v[2] + v[3];
  s[tid] = tsum;
  __syncthreads();
  for (int d = 1; d < 256; d <<= 1) {
    unsigned t = (tid >= d) ? s[tid - d] : 0u;
    __syncthreads();
    s[tid] += t;
    __syncthreads();
  }
  unsigned incl = s[tid];
  unsigned run = incl - tsum;  // exclusive prefix of this thread's chunk
#pragma unroll
  for (int i = 0; i < 4; i++) {
    if (base + i < NBINS) off[base + i] = run;
    run += v[i];
  }
  if (tid == 255) aux[blockIdx.x] = incl;  // block total
}

__global__ void k_scan2(unsigned* __restrict__ aux) {
  __shared__ unsigned s[1024];
  int tid = threadIdx.x;
  unsigned v = (tid < NSCAN) ? aux[tid] : 0u;
  s[tid] = v;
  __syncthreads();
  for (int d = 1; d < 1024; d <<= 1) {
    unsigned t = (tid >= d) ? s[tid - d] : 0u;
    __syncthreads();
    s[tid] += t;
    __syncthreads();
  }
  if (tid < NSCAN) aux[tid] = s[tid] - v;  // exclusive
}

__global__ void k_scan3(unsigned* __restrict__ off, const unsigned* __restrict__ aux,
                        unsigned* __restrict__ cur) {
  int gid = blockIdx.x * blockDim.x + threadIdx.x;
  if (gid >= NBINS) return;
  unsigned v = off[gid] + aux[gid >> 10];
  off[gid] = v;
  cur[gid] = v;
}

__global__ void k_scatter(const int* __restrict__ er, const int* __restrict__ ea,
                          const int* __restrict__ et, unsigned* __restrict__ cur,
                          int* __restrict__ srcbuf) {
  int e = blockIdx.x * blockDim.x + threadIdx.x;
  if (e >= NE) return;
  int a = ea[e], t = et[e], p = er[e];
  unsigned p1 = atomicAdd(&cur[a * RE + t], 1u);
  srcbuf[p1] = p;
  unsigned p2 = atomicAdd(&cur[L2BASE + p * RE + t], 1u);
  srcbuf[p2] = a;
}

// ---------------- h1_repo = relu(h_repo @ root1 + b1) ----------------
__global__ __launch_bounds__(256) void k_rowgemm(const float* __restrict__ A,
                                                 const float* __restrict__ B,
                                                 const float* __restrict__ bias,
                                                 float* __restrict__ C) {
  __shared__ float meanS[32][HD + 1];
  __shared__ float wS[32][HD];
  int tid = threadIdx.x;
  int tu = tid >> 5, to = tid & 31;
  int half = tid >> 7, ch = tid & 127;
  int g0 = blockIdx.x * 32;
  float acc[4][4];
#pragma unroll
  for (int j = 0; j < 4; j++)
#pragma unroll
    for (int k = 0; k < 4; k++) acc[j][k] = 0.f;

  // stage 32 A rows
  for (int pass = 0; pass < 16; pass++) {
    int ul = pass * 2 + half;
    int row = g0 + ul;
    meanS[ul][ch] = (row < NR) ? A[row * HD + ch] : 0.f;
  }
  for (int chunk = 0; chunk < 4; ++chunk) {
    __syncthreads();
#pragma unroll
    for (int i = 0; i < 16; i++) {
      int l = tid + 256 * i;
      int row = l >> 7, col = l & 127;
      wS[row][col] = B[(chunk * 32 + row) * HD + col];
    }
    __syncthreads();
#pragma unroll 8
    for (int hc = 0; hc < 32; ++hc) {
      int h = chunk * 32 + hc;
      float a0 = meanS[4 * tu + 0][h];
      float a1 = meanS[4 * tu + 1][h];
      float a2 = meanS[4 * tu + 2][h];
      float a3 = meanS[4 * tu + 3][h];
      float4 b = *(const float4*)&wS[hc][4 * to];
      acc[0][0] += a0 * b.x; acc[0][1] += a0 * b.y; acc[0][2] += a0 * b.z; acc[0][3] += a0 * b.w;
      acc[1][0] += a1 * b.x; acc[1][1] += a1 * b.y; acc[1][2] += a1 * b.z; acc[1][3] += a1 * b.w;
      acc[2][0] += a2 * b.x; acc[2][1] += a2 * b.y; acc[2][2] += a2 * b.z; acc[2][3] += a2 * b.w;
      acc[3][0] += a3 * b.x; acc[3][1] += a3 * b.y; acc[3][2] += a3 * b.z; acc[3][3] += a3 * b.w;
    }
  }
  float4 bb = *(const float4*)(bias + 4 * to);
#pragma unroll
  for (int j = 0; j < 4; j++) {
    int row = g0 + 4 * tu + j;
    if (row < NR) {
      float4 v;
      v.x = fmaxf(acc[j][0] + bb.x, 0.f);
      v.y = fmaxf(acc[j][1] + bb.y, 0.f);
      v.z = fmaxf(acc[j][2] + bb.z, 0.f);
      v.w = fmaxf(acc[j][3] + bb.w, 0.f);
      *(float4*)(C + row * HD + 4 * to) = v;
    }
  }
}

// ---------------- layer 1: h1_user = relu(sum_r mean_r @ W1[r] + c1) ----------------
__global__ __launch_bounds__(256) void k_layer1(
    const float* __restrict__ hrep, const float* __restrict__ w1,
    const float* __restrict__ c1, const unsigned* __restrict__ off,
    const unsigned* __restrict__ cnt, const int* __restrict__ srcbuf,
    float* __restrict__ h1u) {
  __shared__ float meanS[32][HD + 1];
  __shared__ float wS[32][HD];
  int tid = threadIdx.x;
  int tu = tid >> 5, to = tid & 31;
  int half = tid >> 7, ch = tid & 127;
  int g0 = blockIdx.x * 32;
  float acc[4][4];
  float4 c1v = *(const float4*)(c1 + 4 * to);
#pragma unroll
  for (int j = 0; j < 4; j++) {
    acc[j][0] = c1v.x; acc[j][1] = c1v.y; acc[j][2] = c1v.z; acc[j][3] = c1v.w;
  }
  for (int r = 0; r < RE; r++) {
    __syncthreads();  // meanS safe to overwrite
    for (int pass = 0; pass < 16; pass++) {
      int ul = pass * 2 + half;
      int u = g0 + ul;
      float s = 0.f;
      if (u < NU) {
        unsigned bin = (unsigned)u * RE + r;
        unsigned st = off[bin], c = cnt[bin];
        for (unsigned i = 0; i < c; i++) {
          int src = srcbuf[st + i];
          s += hrep[src * HD + ch];
        }
        if (c > 0) s *= 1.f / (float)c;
      }
      meanS[ul][ch] = s;
    }
    const float* wr = w1 + r * HD * HD;
    for (int chunk = 0; chunk < 4; ++chunk) {
      __syncthreads();
#pragma unroll
      for (int i = 0; i < 16; i++) {
        int l = tid + 256 * i;
        int row = l >> 7, col = l & 127;
        wS[row][col] = wr[(chunk * 32 + row) * HD + col];
      }
      __syncthreads();
#pragma unroll 8
      for (int hc = 0; hc < 32; ++hc) {
        int h = chunk * 32 + hc;
        float a0 = meanS[4 * tu + 0][h];
        float a1 = meanS[4 * tu + 1][h];
        float a2 = meanS[4 * tu + 2][h];
        float a3 = meanS[4 * tu + 3][h];
        float4 b = *(const float4*)&wS[hc][4 * to];
        acc[0][0] += a0 * b.x; acc[0][1] += a0 * b.y; acc[0][2] += a0 * b.z; acc[0][3] += a0 * b.w;
        acc[1][0] += a1 * b.x; acc[1][1] += a1 * b.y; acc[1][2] += a1 * b.z; acc[1][3] += a1 * b.w;
        acc[2][0] += a2 * b.x; acc[2][1] += a2 * b.y; acc[2][2] += a2 * b.z; acc[2][3] += a2 * b.w;
        acc[3][0] += a3 * b.x; acc[3][1] += a3 * b.y; acc[3][2] += a3 * b.z; acc[3][3] += a3 * b.w;
      }
    }
  }
#pragma unroll
  for (int j = 0; j < 4; j++) {
    int u = g0 + 4 * tu + j;
    if (u < NU) {
      float4 v;
      v.x = fmaxf(acc[j][0], 0.f);
      v.y = fmaxf(acc[j][1], 0.f);
      v.z = fmaxf(acc[j][2], 0.f);
      v.w = fmaxf(acc[j][3], 0.f);
      *(float4*)(h1u + u * HD + 4 * to) = v;
    }
  }
}

// ------- layer 2 + root + bias + relu + classifier fused; repos only -------
__global__ __launch_bounds__(256) void k_layer2(
    const float* __restrict__ h1u, const float* __restrict__ h1rep,
    const float* __restrict__ w2, const float* __restrict__ root2,
    const float* __restrict__ b2, const float* __restrict__ clsw,
    const float* __restrict__ clsb, const unsigned* __restrict__ off,
    const unsigned* __restrict__ cnt, const int* __restrict__ srcbuf,
    float* __restrict__ out) {
  __shared__ float meanS[32][HD + 1];
  __shared__ float wS[32][HD];
  __shared__ float red[32][2];
  int tid = threadIdx.x;
  int tu = tid >> 5, to = tid & 31;
  int half = tid >> 7, ch = tid & 127;
  int g0 = blockIdx.x * 32;
  float acc[4][4];
#pragma unroll
  for (int j = 0; j < 4; j++)
#pragma unroll
    for (int k = 0; k < 4; k++) acc[j][k] = 0.f;

  for (int r = 0; r < 9; r++) {
    __syncthreads();
    for (int pass = 0; pass < 16; pass++) {
      int ul = pass * 2 + half;
      int p = g0 + ul;
      float s = 0.f;
      if (p < NR) {
        if (r < 8) {
          unsigned bin = L2BASE + (unsigned)p * RE + r;
          unsigned st = off[bin], c = cnt[bin];
          for (unsigned i = 0; i < c; i++) {
            int src = srcbuf[st + i];
            s += h1u[src * HD + ch];
          }
          if (c > 0) s *= 1.f / (float)c;
        } else {
          s = h1rep[p * HD + ch];  // root pass
        }
      }
      meanS[ul][ch] = s;
    }
    const float* wr = (r < 8) ? (w2 + r * HD * HD) : root2;
    for (int chunk = 0; chunk < 4; ++chunk) {
      __syncthreads();
#pragma unroll
      for (int i = 0; i < 16; i++) {
        int l = tid + 256 * i;
        int row = l >> 7, col = l & 127;
        wS[row][col] = wr[(chunk * 32 + row) * HD + col];
      }
      __syncthreads();
#pragma unroll 8
      for (int hc = 0; hc < 32; ++hc) {
        int h = chunk * 32 + hc;
        float a0 = meanS[4 * tu + 0][h];
        float a1 = meanS[4 * tu + 1][h];
        float a2 = meanS[4 * tu + 2][h];
        float a3 = meanS[4 * tu + 3][h];
        float4 b = *(const float4*)&wS[hc][4 * to];
        acc[0][0] += a0 * b.x; acc[0][1] += a0 * b.y; acc[0][2] += a0 * b.z; acc[0][3] += a0 * b.w;
        acc[1][0] += a1 * b.x; acc[1][1] += a1 * b.y; acc[1][2] += a1 * b.z; acc[1][3] += a1 * b.w;
        acc[2][0] += a2 * b.x; acc[2][1] += a2 * b.y; acc[2][2] += a2 * b.z; acc[2][3] += a2 * b.w;
        acc[3][0] += a3 * b.x; acc[3][1] += a3 * b.y; acc[3][2] += a3 * b.z; acc[3][3] += a3 * b.w;
      }
    }
  }
  // epilogue: h2 = relu(acc + b2); out = h2 @ cls_w + cls_b (never store h2)
  __syncthreads();
  if (tid < 64) red[tid >> 1][tid & 1] = 0.f;
  __syncthreads();
  float4 bb = *(const float4*)(b2 + 4 * to);
  float cw[4][2];
#pragma unroll
  for (int k = 0; k < 4; k++) {
    cw[k][0] = clsw[(4 * to + k) * 2 + 0];
    cw[k][1] = clsw[(4 * to + k) * 2 + 1];
  }
#pragma unroll
  for (int j = 0; j < 4; j++) {
    float y0 = fmaxf(acc[j][0] + bb.x, 0.f);
    float y1 = fmaxf(acc[j][1] + bb.y, 0.f);
    float y2 = fmaxf(acc[j][2] + bb.z, 0.f);
    float y3 = fmaxf(acc[j][3] + bb.w, 0.f);
    float p0 = y0 * cw[0][0] + y1 * cw[1][0] + y2 * cw[2][0] + y3 * cw[3][0];
    float p1 = y0 * cw[0][1] + y1 * cw[1][1] + y2 * cw[2][1] + y3 * cw[3][1];
    atomicAdd(&red[4 * tu + j][0], p0);
    atomicAdd(&red[4 * tu + j][1], p1);
  }
  __syncthreads();
  if (tid < 64) {
    int u = tid >> 1, c = tid & 1;
    int p = g0 + u;
    if (p < NR) out[p * 2 + c] = red[u][c] + clsb[c];
  }
}

extern "C" void kernel_launch(void* const* d_in, const int* in_sizes, int n_in,
                              void* d_out, int out_size, void* d_ws, size_t ws_size,
                              hipStream_t stream) {
  const float* x = (const float*)d_in[0];
  const int* er = (const int*)d_in[1];
  const int* ea = (const int*)d_in[2];
  const int* et = (const int*)d_in[3];
  const float* mw = (const float*)d_in[4];
  const float* mb = (const float*)d_in[5];
  const float* w1 = (const float*)d_in[6];
  const float* root1 = (const float*)d_in[7];
  const float* b1 = (const float*)d_in[8];
  const float* w2 = (const float*)d_in[9];
  const float* root2 = (const float*)d_in[10];
  const float* b2 = (const float*)d_in[11];
  const float* clsw = (const float*)d_in[12];
  const float* clsb = (const float*)d_in[13];
  float* out = (float*)d_out;

  char* w = (char*)d_ws;
  size_t ofs = 0;
  auto alloc = [&](size_t bytes) {
    void* p = w + ofs;
    ofs = (ofs + bytes + 255) & ~(size_t)255;
    return p;
  };
  unsigned* cnt = (unsigned*)alloc(NBINS * 4);
  unsigned* off = (unsigned*)alloc(NBINS * 4);
  unsigned* cur = (unsigned*)alloc(NBINS * 4);
  unsigned* aux = (unsigned*)alloc(1024 * 4);
  int* srcbuf = (int*)alloc((size_t)2 * NE * 4);
  float* hrep = (float*)alloc((size_t)NR * HD * 4);
  float* h1u = (float*)alloc((size_t)NU * HD * 4);
  float* h1rep = (float*)alloc((size_t)NR * HD * 4);
  float* c1 = (float*)alloc(HD * 4);

  hipMemsetAsync(cnt, 0, NBINS * 4, stream);
  k_mlp<<<(NR * HD + 255) / 256, 256, 0, stream>>>(x, mw, mb, hrep);
  k_c1<<<1, 128, 0, stream>>>(mb, root1, b1, c1);
  k_hist<<<(NE + 255) / 256, 256, 0, stream>>>(er, ea, et, cnt);
  k_scan1<<<NSCAN, 256, 0, stream>>>(cnt, off, aux);
  k_scan2<<<1, 1024, 0, stream>>>(aux);
  k_scan3<<<(NBINS + 255) / 256, 256, 0, stream>>>(off, aux, cur);
  k_scatter<<<(NE + 255) / 256, 256, 0, stream>>>(er, ea, et, cur, srcbuf);
  k_rowgemm<<<(NR + 31) / 32, 256, 0, stream>>>(hrep, root1, b1, h1rep);
  k_layer1<<<(NU + 31) / 32, 256, 0, stream>>>(hrep, w1, c1, off, cnt, srcbuf, h1u);
  k_layer2<<<(NR + 31) / 32, 256, 0, stream>>>(h1u, h1rep, w2, root2, b2, clsw, clsb,
                                               off, cnt, srcbuf, out);
}

// Round 26
// 660.809 us; speedup vs baseline: 2.9211x; 2.9211x over previous
//
#include <hip/hip_runtime.h>
#include <hip/hip_bf16.h>
typedef unsigned int u32; typedef unsigned short u16;
typedef __attribute__((ext_vector_type(8))) u16 us8;
#define NR 30000
#define NU 70000
#define RE 8
#define HD 128
#define NE 1000000
#define NBINS ((NU+NR)*RE)
#define L2BASE (NU*RE)
#define NSCAN ((NBINS+1023)/1024)
__device__ __forceinline__ u16 f2b(float f){u32 x=__builtin_bit_cast(u32,f);x+=0x7fffu+((x>>16)&1u);return (u16)(x>>16);}
__device__ __forceinline__ float b2f_lo(u32 w){return __builtin_bit_cast(float,w<<16);}
__device__ __forceinline__ float b2f_hi(u32 w){return __builtin_bit_cast(float,w&0xffff0000u);}
__device__ __forceinline__ u32 packbf(float a,float b){return (u32)f2b(a)|((u32)f2b(b)<<16);}

__global__ void k_mlp(const float* __restrict__ x,const float* __restrict__ mw,const float* __restrict__ mb,float* __restrict__ h){
  int gid=blockIdx.x*blockDim.x+threadIdx.x; if(gid>=NR*HD)return;
  int j=gid>>7,o=gid&127; float acc=mb[o]; const float* xr=x+j*8;
#pragma unroll
  for(int i=0;i<8;i++)acc+=xr[i]*mw[i*HD+o];
  h[gid]=fmaxf(acc,0.f);
}
__global__ void k_c1(const float* __restrict__ mb,const float* __restrict__ root1,const float* __restrict__ b1,float* __restrict__ c1){
  __shared__ float hu[HD]; int t=threadIdx.x;
  hu[t]=fmaxf(mb[t],0.f); __syncthreads();
  float acc=b1[t];
  for(int h=0;h<HD;++h)acc+=hu[h]*root1[h*HD+t];
  c1[t]=acc;
}
__global__ void k_hist(const int* __restrict__ er,const int* __restrict__ ea,const int* __restrict__ et,unsigned* __restrict__ cnt){
  int e=blockIdx.x*blockDim.x+threadIdx.x; if(e>=NE)return;
  int a=ea[e],t=et[e],p=er[e];
  atomicAdd(&cnt[a*RE+t],1u); atomicAdd(&cnt[L2BASE+p*RE+t],1u);
}
__global__ void k_scan1(const unsigned* __restrict__ cnt,unsigned* __restrict__ off,unsigned* __restrict__ aux){
  __shared__ unsigned s[256]; int tid=threadIdx.x; int base=blockIdx.x*1024+tid*4;
  unsigned v[4];
#pragma unroll
  for(int i=0;i<4;i++)v[i]=(base+i<NBINS)?cnt[base+i]:0u;
  unsigned tsum=v[0]+v[1]+v[2]+v[3]; s[tid]=tsum; __syncthreads();
  for(int d=1;d<256;d<<=1){unsigned t=(tid>=d)?s[tid-d]:0u;__syncthreads();s[tid]+=t;__syncthreads();}
  unsigned incl=s[tid]; unsigned run=incl-tsum;
#pragma unroll
  for(int i=0;i<4;i++){if(base+i<NBINS)off[base+i]=run; run+=v[i];}
  if(tid==255)aux[blockIdx.x]=incl;
}
__global__ void k_scan2(unsigned* __restrict__ aux){
  __shared__ unsigned s[1024]; int tid=threadIdx.x;
  unsigned v=(tid<NSCAN)?aux[tid]:0u; s[tid]=v; __syncthreads();
  for(int d=1;d<1024;d<<=1){unsigned t=(tid>=d)?s[tid-d]:0u;__syncthreads();s[tid]+=t;__syncthreads();}
  if(tid<NSCAN)aux[tid]=s[tid]-v;
}
__global__ void k_scan3(unsigned* __restrict__ off,const unsigned* __restrict__ aux,unsigned* __restrict__ cur,const unsigned* __restrict__ cnt,float* __restrict__ invc){
  int gid=blockIdx.x*blockDim.x+threadIdx.x; if(gid>=NBINS)return;
  unsigned v=off[gid]+aux[gid>>10]; off[gid]=v; cur[gid]=v;
  unsigned c=cnt[gid]; invc[gid]=1.0f/(float)(c?c:1u);
}
__global__ void k_scatter(const int* __restrict__ er,const int* __restrict__ ea,const int* __restrict__ et,unsigned* __restrict__ cur,int* __restrict__ srcbuf){
  int e=blockIdx.x*blockDim.x+threadIdx.x; if(e>=NE)return;
  int a=ea[e],t=et[e],p=er[e];
  unsigned p1=atomicAdd(&cur[a*RE+t],1u); srcbuf[p1]=(p<<3)|t;
  unsigned p2=atomicAdd(&cur[L2BASE+p*RE+t],1u); srcbuf[p2]=(a<<3)|t;
}
// EPI 0: bf16 store; bias!=nullptr -> +bias, relu first. EPI 2: fused classifier.
template<bool ABF16,int EPI,int KSTEPS,int KTILE,int KSPLIT>
__global__ __launch_bounds__(256) void k_gemm(const void* __restrict__ Av,const float* __restrict__ B,const float* __restrict__ B2,const float* __restrict__ bias,void* __restrict__ Cv,const float* __restrict__ clsw,const float* __restrict__ clsb,int M,int lda,int ldc,int npanel){
  __shared__ float As[64][KTILE*32+4];
  __shared__ float Bs[32][132];
  const int tid=threadIdx.x; const int tx=tid&15,ty=tid>>4; const int g0=blockIdx.x*64;
  if(KTILE==KSTEPS){
    const float* A=(const float*)Av;
#pragma unroll
    for(int i=0;i<2*KTILE;i++){
      int f=tid+256*i; int row=f/(KTILE*8); int c4=f%(KTILE*8); int gr=g0+row;
      float4 v=make_float4(0.f,0.f,0.f,0.f);
      if(gr<M)v=*(const float4*)(A+(size_t)gr*lda+c4*4);
      *(float4*)&As[row][c4*4]=v;
    }
  }
  float acc[4][8];
#pragma unroll 1
  for(int pnl=0;pnl<npanel;pnl++){
#pragma unroll
    for(int j=0;j<4;j++)
#pragma unroll
      for(int c=0;c<8;c++)acc[j][c]=0.f;
#pragma unroll 1
    for(int ks=0;ks<KSTEPS;ks++){
      __syncthreads();
      if(KTILE==1){
        int row=tid>>2,col=(tid&3)*8; int gr=g0+row;
        if(ABF16){
          float tmp[8];
          if(gr<M){
            us8 av=*(const us8*)((const u16*)Av+(size_t)gr*lda+ks*32+col);
#pragma unroll
            for(int q=0;q<8;q++)tmp[q]=__builtin_bit_cast(float,(u32)av[q]<<16);
          }else{
#pragma unroll
            for(int q=0;q<8;q++)tmp[q]=0.f;
          }
#pragma unroll
          for(int q=0;q<8;q++)As[row][col+q]=tmp[q];
        }else{
          const float* A=(const float*)Av;
          float4 v0=make_float4(0,0,0,0),v1=v0;
          if(gr<M){v0=*(const float4*)(A+(size_t)gr*lda+ks*32+col);v1=*(const float4*)(A+(size_t)gr*lda+ks*32+col+4);}
          *(float4*)&As[row][col]=v0; *(float4*)&As[row][col+4]=v1;
        }
      }
      {
        const float* Bsrc=(ks>=KSPLIT)?(B2+(size_t)(ks-KSPLIT)*32*128):(B+(size_t)pnl*(KSTEPS*32*128)+(size_t)ks*32*128);
#pragma unroll
        for(int i=0;i<4;i++){
          int f=tid+256*i; int row=f>>5,c4=f&31;
          float4 v=*(const float4*)(Bsrc+(size_t)row*128+c4*4);
          *(float4*)&Bs[row][c4*4]=v;
        }
      }
      __syncthreads();
#pragma unroll
      for(int kk=0;kk<32;kk++){
        int kcol=(KTILE==1)?kk:ks*32+kk;
        float aa[4];
#pragma unroll
        for(int j=0;j<4;j++)aa[j]=As[ty*4+j][kcol];
        float4 b0=*(const float4*)&Bs[kk][tx*8];
        float4 b1=*(const float4*)&Bs[kk][tx*8+4];
        float bb[8]={b0.x,b0.y,b0.z,b0.w,b1.x,b1.y,b1.z,b1.w};
#pragma unroll
        for(int j=0;j<4;j++)
#pragma unroll
          for(int c=0;c<8;c++)acc[j][c]=fmaf(aa[j],bb[c],acc[j][c]);
      }
    }
    if(EPI==0){
      u16* C=(u16*)Cv;
      float bv[8];
#pragma unroll
      for(int c=0;c<8;c++)bv[c]=bias?bias[tx*8+c]:0.f;
#pragma unroll
      for(int j=0;j<4;j++){
        int row=g0+ty*4+j;
        if(row<M){
          us8 pv;
#pragma unroll
          for(int c=0;c<8;c++){
            float y=acc[j][c];
            if(bias)y=fmaxf(y+bv[c],0.f);
            pv[c]=f2b(y);
          }
          *(us8*)(C+(size_t)row*ldc+pnl*128+tx*8)=pv;
        }
      }
    }else{
      float* out=(float*)Cv;
      float bv[8],cw0[8],cw1[8];
#pragma unroll
      for(int c=0;c<8;c++){bv[c]=bias[tx*8+c];cw0[c]=clsw[(tx*8+c)*2];cw1[c]=clsw[(tx*8+c)*2+1];}
#pragma unroll
      for(int j=0;j<4;j++){
        float o0=0.f,o1=0.f;
#pragma unroll
        for(int c=0;c<8;c++){
          float y=fmaxf(acc[j][c]+bv[c],0.f);
          o0=fmaf(y,cw0[c],o0); o1=fmaf(y,cw1[c],o1);
        }
#pragma unroll
        for(int d=1;d<16;d<<=1){o0+=__shfl_xor(o0,d);o1+=__shfl_xor(o1,d);}
        if(tx==0){
          int row=g0+ty*4+j;
          if(row<M){out[(size_t)row*2]=o0+clsb[0];out[(size_t)row*2+1]=o1+clsb[1];}
        }
      }
    }
  }
}
#define DECL_ACCS float s00=0,s01=0,s10=0,s11=0,s20=0,s21=0,s30=0,s31=0,s40=0,s41=0,s50=0,s51=0,s60=0,s61=0,s70=0,s71=0;
#define ACCV(v,w){float lo=b2f_lo(w),hi=b2f_hi(w);switch((v)&7u){case 0:s00+=lo;s01+=hi;break;case 1:s10+=lo;s11+=hi;break;case 2:s20+=lo;s21+=hi;break;case 3:s30+=lo;s31+=hi;break;case 4:s40+=lo;s41+=hi;break;case 5:s50+=lo;s51+=hi;break;case 6:s60+=lo;s61+=hi;break;case 7:s70+=lo;s71+=hi;break;}}
__global__ __launch_bounds__(256) void k_agg1(const u16* __restrict__ y1b,const unsigned* __restrict__ off,const unsigned* __restrict__ cnt,const float* __restrict__ invc,const int* __restrict__ srcbuf,const float* __restrict__ c1,u16* __restrict__ h1ub){
  int u=(blockIdx.x*blockDim.x+threadIdx.x)>>6; int lane=threadIdx.x&63;
  if(u>=NU)return;
  unsigned base=(unsigned)u*RE; unsigned e=off[base]; unsigned end=off[base+7]+cnt[base+7];
  DECL_ACCS
#define LDY(v) (*(const u32*)(y1b+(((size_t)(v))<<7)+(lane<<1)))
  for(;e+4<=end;e+=4){
    u32 v0=(u32)srcbuf[e],v1=(u32)srcbuf[e+1];
    u32 v2=(u32)srcbuf[e+2],v3=(u32)srcbuf[e+3];
    u32 w0=LDY(v0),w1=LDY(v1),w2=LDY(v2),w3=LDY(v3);
    ACCV(v0,w0) ACCV(v1,w1) ACCV(v2,w2) ACCV(v3,w3)
  }
  for(;e<end;e++){u32 v=(u32)srcbuf[e];u32 w=LDY(v);ACCV(v,w)}
  float4 i0=*(const float4*)(invc+base);
  float4 i1=*(const float4*)(invc+base+4);
  float2 cv=*(const float2*)(c1+lane*2);
  float m0=cv.x+s00*i0.x+s10*i0.y+s20*i0.z+s30*i0.w+s40*i1.x+s50*i1.y+s60*i1.z+s70*i1.w;
  float m1=cv.y+s01*i0.x+s11*i0.y+s21*i0.z+s31*i0.w+s41*i1.x+s51*i1.y+s61*i1.z+s71*i1.w;
  m0=fmaxf(m0,0.f); m1=fmaxf(m1,0.f);
  *(u32*)(h1ub+(size_t)u*HD+lane*2)=packbf(m0,m1);
}
__global__ __launch_bounds__(256) void k_agg2(const u16* __restrict__ h1ub,const u16* __restrict__ h1repb,const unsigned* __restrict__ off,const unsigned* __restrict__ cnt,const float* __restrict__ invc,const int* __restrict__ srcbuf,u16* __restrict__ mbuf){
  int p=(blockIdx.x*blockDim.x+threadIdx.x)>>6; int lane=threadIdx.x&63;
  if(p>=NR)return;
  unsigned base=L2BASE+(unsigned)p*RE; unsigned e=off[base]; unsigned end=off[base+7]+cnt[base+7];
  DECL_ACCS
#define LDH(v) (*(const u32*)(h1ub+(((size_t)((v)>>3))<<7)+(lane<<1)))
  for(;e+4<=end;e+=4){
    u32 v0=(u32)srcbuf[e],v1=(u32)srcbuf[e+1];
    u32 v2=(u32)srcbuf[e+2],v3=(u32)srcbuf[e+3];
    u32 w0=LDH(v0),w1=LDH(v1),w2=LDH(v2),w3=LDH(v3);
    ACCV(v0,w0) ACCV(v1,w1) ACCV(v2,w2) ACCV(v3,w3)
  }
  for(;e<end;e++){u32 v=(u32)srcbuf[e];u32 w=LDH(v);ACCV(v,w)}
  float4 i0=*(const float4*)(invc+base);
  float4 i1=*(const float4*)(invc+base+4);
  u16* rowp=mbuf+(size_t)p*1152;
#define STM(r,ic) *(u32*)(rowp+(r)*128+lane*2)=packbf(s##r##0*(ic),s##r##1*(ic));
  STM(0,i0.x) STM(1,i0.y) STM(2,i0.z) STM(3,i0.w)
  STM(4,i1.x) STM(5,i1.y) STM(6,i1.z) STM(7,i1.w)
  *(u32*)(rowp+1024+lane*2)=*(const u32*)(h1repb+(size_t)p*HD+lane*2);
}
extern "C" void kernel_launch(void* const* d_in,const int* in_sizes,int n_in,void* d_out,int out_size,void* d_ws,size_t ws_size,hipStream_t stream){
  const float* x=(const float*)d_in[0];
  const int* er=(const int*)d_in[1];
  const int* ea=(const int*)d_in[2];
  const int* et=(const int*)d_in[3];
  const float* mw=(const float*)d_in[4];
  const float* mb=(const float*)d_in[5];
  const float* w1=(const float*)d_in[6];
  const float* root1=(const float*)d_in[7];
  const float* b1=(const float*)d_in[8];
  const float* w2=(const float*)d_in[9];
  const float* root2=(const float*)d_in[10];
  const float* b2=(const float*)d_in[11];
  const float* clsw=(const float*)d_in[12];
  const float* clsb=(const float*)d_in[13];
  float* out=(float*)d_out;
  char* w=(char*)d_ws; size_t ofs=0;
  auto alloc=[&](size_t bytes){void* p=w+ofs;ofs=(ofs+bytes+255)&~(size_t)255;return p;};
  unsigned* cnt=(unsigned*)alloc(NBINS*4);
  unsigned* off=(unsigned*)alloc(NBINS*4);
  unsigned* cur=(unsigned*)alloc(NBINS*4);
  float* invc=(float*)alloc(NBINS*4);
  unsigned* aux=(unsigned*)alloc(1024*4);
  int* srcbuf=(int*)alloc((size_t)2*NE*4);
  float* hrep=(float*)alloc((size_t)NR*HD*4);
  u16* h1repb=(u16*)alloc((size_t)NR*HD*2);
  float* c1=(float*)alloc(HD*4);
  u16* h1ub=(u16*)alloc((size_t)NU*HD*2);
  u16* mbuf=(u16*)alloc((size_t)NR*1152*2);
  u16* y1b=mbuf;
  hipMemsetAsync(cnt,0,NBINS*4,stream);
  k_mlp<<<(NR*HD+255)/256,256,0,stream>>>(x,mw,mb,hrep);
  k_c1<<<1,128,0,stream>>>(mb,root1,b1,c1);
  k_hist<<<(NE+255)/256,256,0,stream>>>(er,ea,et,cnt);
  k_scan1<<<NSCAN,256,0,stream>>>(cnt,off,aux);
  k_scan2<<<1,1024,0,stream>>>(aux);
  k_scan3<<<(NBINS+255)/256,256,0,stream>>>(off,aux,cur,cnt,invc);
  k_scatter<<<(NE+255)/256,256,0,stream>>>(er,ea,et,cur,srcbuf);
  // Y1 = hrep @ [W1_r]: bf16 store, no bias (bias=nullptr), 8 panels
  k_gemm<false,0,4,4,4><<<(NR+63)/64,256,0,stream>>>(hrep,w1,nullptr,nullptr,y1b,nullptr,nullptr,NR,HD,1024,8);
  // h1rep = relu(hrep @ root1 + b1): same instantiation, bias=b1, 1 panel
  k_gemm<false,0,4,4,4><<<(NR+63)/64,256,0,stream>>>(hrep,root1,nullptr,b1,h1repb,nullptr,nullptr,NR,HD,HD,1);
  k_agg1<<<NU/4,256,0,stream>>>(y1b,off,cnt,invc,srcbuf,c1,h1ub);
  k_agg2<<<NR/4,256,0,stream>>>(h1ub,h1repb,off,cnt,invc,srcbuf,mbuf);
  // out = relu(Mbuf @ [w2;root2] + b2) @ clsw + clsb
  k_gemm<true,2,36,1,32><<<(NR+63)/64,256,0,stream>>>(mbuf,w2,root2,b2,out,clsw,clsb,NR,1152,0,1);
}

// Round 29
// 478.452 us; speedup vs baseline: 4.0345x; 1.3811x over previous
//
#include <hip/hip_runtime.h>
#include <hip/hip_bf16.h>
typedef unsigned int u32; typedef unsigned short u16;
typedef __attribute__((ext_vector_type(8))) u16 us8;
typedef __attribute__((ext_vector_type(8))) __bf16 bf16x8;
typedef __attribute__((ext_vector_type(4))) float f32x4;
#define NR 30000
#define NU 70000
#define RE 8
#define HD 128
#define NE 1000000
#define NBINS ((NU+NR)*RE)
#define L2BASE (NU*RE)
#define NSCAN ((NBINS+1023)/1024)
__device__ __forceinline__ u16 f2b(float f){u32 x=__builtin_bit_cast(u32,f);x+=0x7fffu+((x>>16)&1u);return (u16)(x>>16);}
__device__ __forceinline__ float b2f_lo(u32 w){return __builtin_bit_cast(float,w<<16);}
__device__ __forceinline__ float b2f_hi(u32 w){return __builtin_bit_cast(float,w&0xffff0000u);}
__device__ __forceinline__ u32 packbf(float a,float b){return (u32)f2b(a)|((u32)f2b(b)<<16);}

__global__ void k_mlp(const float* __restrict__ x,const float* __restrict__ mw,const float* __restrict__ mb,u16* __restrict__ h){
  int gid=blockIdx.x*blockDim.x+threadIdx.x; if(gid>=NR*HD)return;
  int j=gid>>7,o=gid&127; float acc=mb[o]; const float* xr=x+j*8;
#pragma unroll
  for(int i=0;i<8;i++)acc+=xr[i]*mw[i*HD+o];
  h[gid]=f2b(fmaxf(acc,0.f));
}
__global__ void k_c1(const float* __restrict__ mb,const float* __restrict__ root1,const float* __restrict__ b1,float* __restrict__ c1){
  __shared__ float hu[HD]; int t=threadIdx.x;
  hu[t]=fmaxf(mb[t],0.f); __syncthreads();
  float acc=b1[t];
  for(int h=0;h<HD;++h)acc+=hu[h]*root1[h*HD+t];
  c1[t]=acc;
}
__global__ void k_hist(const int* __restrict__ er,const int* __restrict__ ea,const int* __restrict__ et,unsigned* __restrict__ cnt){
  int e=blockIdx.x*blockDim.x+threadIdx.x; if(e>=NE)return;
  int a=ea[e],t=et[e],p=er[e];
  atomicAdd(&cnt[a*RE+t],1u); atomicAdd(&cnt[L2BASE+p*RE+t],1u);
}
__global__ void k_scan1(const unsigned* __restrict__ cnt,unsigned* __restrict__ off,unsigned* __restrict__ aux){
  __shared__ unsigned s[256]; int tid=threadIdx.x; int base=blockIdx.x*1024+tid*4;
  unsigned v[4];
#pragma unroll
  for(int i=0;i<4;i++)v[i]=(base+i<NBINS)?cnt[base+i]:0u;
  unsigned tsum=v[0]+v[1]+v[2]+v[3]; s[tid]=tsum; __syncthreads();
  for(int d=1;d<256;d<<=1){unsigned t=(tid>=d)?s[tid-d]:0u;__syncthreads();s[tid]+=t;__syncthreads();}
  unsigned incl=s[tid]; unsigned run=incl-tsum;
#pragma unroll
  for(int i=0;i<4;i++){if(base+i<NBINS)off[base+i]=run; run+=v[i];}
  if(tid==255)aux[blockIdx.x]=incl;
}
__global__ void k_scan2(unsigned* __restrict__ aux){
  __shared__ unsigned s[1024]; int tid=threadIdx.x;
  unsigned v=(tid<NSCAN)?aux[tid]:0u; s[tid]=v; __syncthreads();
  for(int d=1;d<1024;d<<=1){unsigned t=(tid>=d)?s[tid-d]:0u;__syncthreads();s[tid]+=t;__syncthreads();}
  if(tid<NSCAN)aux[tid]=s[tid]-v;
}
__global__ void k_scan3(unsigned* __restrict__ off,const unsigned* __restrict__ aux,unsigned* __restrict__ cur,const unsigned* __restrict__ cnt,float* __restrict__ invc){
  int gid=blockIdx.x*blockDim.x+threadIdx.x; if(gid>=NBINS)return;
  unsigned v=off[gid]+aux[gid>>10]; off[gid]=v; cur[gid]=v;
  unsigned c=cnt[gid]; invc[gid]=1.0f/(float)(c?c:1u);
}
__global__ void k_scatter(const int* __restrict__ er,const int* __restrict__ ea,const int* __restrict__ et,unsigned* __restrict__ cur,int* __restrict__ srcbuf){
  int e=blockIdx.x*blockDim.x+threadIdx.x; if(e>=NE)return;
  int a=ea[e],t=et[e],p=er[e];
  unsigned p1=atomicAdd(&cur[a*RE+t],1u); srcbuf[p1]=(p<<3)|t;
  unsigned p2=atomicAdd(&cur[L2BASE+p*RE+t],1u); srcbuf[p2]=(a<<3)|t;
}
// pack B weights into MFMA fragment layout: frag id f, lane l, elem j ->
// B[k0+(l>>4)*8+j][nt*16+(l&15)].  w1: f=r*32+kt*8+nt (256); root1: 256+kt*8+nt (32);
// cls: 288+kt*8+nt, kt<36, k=kt*32+..: k<1024 from w2 else root2 (288). total 576 frags.
__global__ void k_pack(const float* __restrict__ w1,const float* __restrict__ root1,const float* __restrict__ w2,const float* __restrict__ root2,u16* __restrict__ pack){
  int gid=blockIdx.x*blockDim.x+threadIdx.x;
  if(gid>=576*512)return;
  int f=gid>>9, e=gid&511, l=e>>3, j=e&7;
  int kin=(l>>4)*8+j, n=(f&7)*16+(l&15);
  float v;
  if(f<256){ int r=f>>5, kt=(f>>3)&3; v=w1[r*16384+(kt*32+kin)*128+n]; }
  else if(f<288){ int kt=(f-256)>>3; v=root1[(kt*32+kin)*128+n]; }
  else{ int kt=(f-288)>>3; int k=kt*32+kin; v=(k<1024)?w2[k*128+n]:root2[(k-1024)*128+n]; }
  pack[gid]=f2b(v);
}
// MFMA gemm: block=256 thr=4 waves; wave tile 16 rows x 64 cols; block 32 rows x 128 cols.
// panel = blockIdx.y (fragbase0 + by*32). EPI 0: bf16 store (+bias,relu if bias). EPI 2: classifier.
template<int KSTEPS,int EPI>
__global__ __launch_bounds__(256) void k_mgemm(const u16* __restrict__ A,const u16* __restrict__ pack,int fragbase0,const float* __restrict__ bias,void* __restrict__ Cv,const float* __restrict__ clsw,const float* __restrict__ clsb,int M,int lda,int ldc){
  __shared__ float red[32][2];
  const int tid=threadIdx.x, l=tid&63, wid=tid>>6;
  const int nh=wid&1, rh=wid>>1, kgrp=l>>4, ln=l&15;
  const int by=blockIdx.y;
  const int rbase=blockIdx.x*32+rh*16;
  const int row_a=rbase+ln;
  if(EPI==2){ if(tid<64){red[tid>>1][tid&1]=0.f;} __syncthreads(); }
  const us8 ZV={0,0,0,0,0,0,0,0};
  f32x4 acc0={0.f,0.f,0.f,0.f},acc1=acc0,acc2=acc0,acc3=acc0;
#pragma unroll 1
  for(int kt=0;kt<KSTEPS;kt++){
    bf16x8 a;
    if(row_a<M) a=__builtin_bit_cast(bf16x8,*(const us8*)(A+(size_t)row_a*lda+kt*32+kgrp*8));
    else a=__builtin_bit_cast(bf16x8,ZV);
    const u16* pb=pack+(size_t)(fragbase0+by*32+kt*8+nh*4)*512+l*8;
    bf16x8 b0=__builtin_bit_cast(bf16x8,*(const us8*)(pb));
    bf16x8 b1=__builtin_bit_cast(bf16x8,*(const us8*)(pb+512));
    bf16x8 b2=__builtin_bit_cast(bf16x8,*(const us8*)(pb+1024));
    bf16x8 b3=__builtin_bit_cast(bf16x8,*(const us8*)(pb+1536));
    acc0=__builtin_amdgcn_mfma_f32_16x16x32_bf16(a,b0,acc0,0,0,0);
    acc1=__builtin_amdgcn_mfma_f32_16x16x32_bf16(a,b1,acc1,0,0,0);
    acc2=__builtin_amdgcn_mfma_f32_16x16x32_bf16(a,b2,acc2,0,0,0);
    acc3=__builtin_amdgcn_mfma_f32_16x16x32_bf16(a,b3,acc3,0,0,0);
  }
  if(EPI==0){
    u16* C=(u16*)Cv;
    f32x4 av[4]={acc0,acc1,acc2,acc3};
#pragma unroll
    for(int q=0;q<4;q++){
      int colp=nh*64+q*16+ln;
      float bv=bias?bias[colp]:0.f;
#pragma unroll
      for(int i=0;i<4;i++){
        int rowc=rbase+kgrp*4+i;
        if(rowc<M){
          float y=av[q][i];
          if(bias)y=fmaxf(y+bv,0.f);
          C[(size_t)rowc*ldc+by*128+colp]=f2b(y);
        }
      }
    }
  }else{
    float* out=(float*)Cv;
    f32x4 av[4]={acc0,acc1,acc2,acc3};
    float bv[4],c0[4],c1[4];
#pragma unroll
    for(int q=0;q<4;q++){
      int colp=nh*64+q*16+ln;
      bv[q]=bias[colp]; c0[q]=clsw[colp*2]; c1[q]=clsw[colp*2+1];
    }
#pragma unroll
    for(int i=0;i<4;i++){
      float o0=0.f,o1=0.f;
#pragma unroll
      for(int q=0;q<4;q++){
        float y=fmaxf(av[q][i]+bv[q],0.f);
        o0=fmaf(y,c0[q],o0); o1=fmaf(y,c1[q],o1);
      }
#pragma unroll
      for(int d=1;d<16;d<<=1){o0+=__shfl_xor(o0,d);o1+=__shfl_xor(o1,d);}
      if(ln==0){
        int rl=rh*16+kgrp*4+i;
        atomicAdd(&red[rl][0],o0); atomicAdd(&red[rl][1],o1);
      }
    }
    __syncthreads();
    if(tid<64){
      int p=tid>>1,c=tid&1; int row=blockIdx.x*32+p;
      if(row<M) out[(size_t)row*2+c]=red[p][c]+clsb[c];
    }
  }
}
#define DECL_ACCS float s00=0,s01=0,s10=0,s11=0,s20=0,s21=0,s30=0,s31=0,s40=0,s41=0,s50=0,s51=0,s60=0,s61=0,s70=0,s71=0;
#define ACCV(v,w){float lo=b2f_lo(w),hi=b2f_hi(w);switch((v)&7u){case 0:s00+=lo;s01+=hi;break;case 1:s10+=lo;s11+=hi;break;case 2:s20+=lo;s21+=hi;break;case 3:s30+=lo;s31+=hi;break;case 4:s40+=lo;s41+=hi;break;case 5:s50+=lo;s51+=hi;break;case 6:s60+=lo;s61+=hi;break;case 7:s70+=lo;s71+=hi;break;}}
__global__ __launch_bounds__(256) void k_agg1(const u16* __restrict__ y1b,const unsigned* __restrict__ off,const unsigned* __restrict__ cnt,const float* __restrict__ invc,const int* __restrict__ srcbuf,const float* __restrict__ c1,u16* __restrict__ h1ub){
  int u=(blockIdx.x*blockDim.x+threadIdx.x)>>6; int lane=threadIdx.x&63;
  if(u>=NU)return;
  unsigned base=(unsigned)u*RE; unsigned e=off[base]; unsigned end=off[base+7]+cnt[base+7];
  DECL_ACCS
#define LDY(v) (*(const u32*)(y1b+(((size_t)(v))<<7)+(lane<<1)))
  for(;e+4<=end;e+=4){
    u32 v0=(u32)srcbuf[e],v1=(u32)srcbuf[e+1];
    u32 v2=(u32)srcbuf[e+2],v3=(u32)srcbuf[e+3];
    u32 w0=LDY(v0),w1=LDY(v1),w2=LDY(v2),w3=LDY(v3);
    ACCV(v0,w0) ACCV(v1,w1) ACCV(v2,w2) ACCV(v3,w3)
  }
  for(;e<end;e++){u32 v=(u32)srcbuf[e];u32 w=LDY(v);ACCV(v,w)}
  float4 i0=*(const float4*)(invc+base);
  float4 i1=*(const float4*)(invc+base+4);
  float2 cv=*(const float2*)(c1+lane*2);
  float m0=cv.x+s00*i0.x+s10*i0.y+s20*i0.z+s30*i0.w+s40*i1.x+s50*i1.y+s60*i1.z+s70*i1.w;
  float m1=cv.y+s01*i0.x+s11*i0.y+s21*i0.z+s31*i0.w+s41*i1.x+s51*i1.y+s61*i1.z+s71*i1.w;
  m0=fmaxf(m0,0.f); m1=fmaxf(m1,0.f);
  *(u32*)(h1ub+(size_t)u*HD+lane*2)=packbf(m0,m1);
}
__global__ __launch_bounds__(256) void k_agg2(const u16* __restrict__ h1ub,const u16* __restrict__ h1repb,const unsigned* __restrict__ off,const unsigned* __restrict__ cnt,const float* __restrict__ invc,const int* __restrict__ srcbuf,u16* __restrict__ mbuf){
  int p=(blockIdx.x*blockDim.x+threadIdx.x)>>6; int lane=threadIdx.x&63;
  if(p>=NR)return;
  unsigned base=L2BASE+(unsigned)p*RE; unsigned e=off[base]; unsigned end=off[base+7]+cnt[base+7];
  DECL_ACCS
#define LDH(v) (*(const u32*)(h1ub+(((size_t)((v)>>3))<<7)+(lane<<1)))
  for(;e+4<=end;e+=4){
    u32 v0=(u32)srcbuf[e],v1=(u32)srcbuf[e+1];
    u32 v2=(u32)srcbuf[e+2],v3=(u32)srcbuf[e+3];
    u32 w0=LDH(v0),w1=LDH(v1),w2=LDH(v2),w3=LDH(v3);
    ACCV(v0,w0) ACCV(v1,w1) ACCV(v2,w2) ACCV(v3,w3)
  }
  for(;e<end;e++){u32 v=(u32)srcbuf[e];u32 w=LDH(v);ACCV(v,w)}
  float4 i0=*(const float4*)(invc+base);
  float4 i1=*(const float4*)(invc+base+4);
  u16* rowp=mbuf+(size_t)p*1152;
#define STM(r,ic) *(u32*)(rowp+(r)*128+lane*2)=packbf(s##r##0*(ic),s##r##1*(ic));
  STM(0,i0.x) STM(1,i0.y) STM(2,i0.z) STM(3,i0.w)
  STM(4,i1.x) STM(5,i1.y) STM(6,i1.z) STM(7,i1.w)
  *(u32*)(rowp+1024+lane*2)=*(const u32*)(h1repb+(size_t)p*HD+lane*2);
}
extern "C" void kernel_launch(void* const* d_in,const int* in_sizes,int n_in,void* d_out,int out_size,void* d_ws,size_t ws_size,hipStream_t stream){
  const float* x=(const float*)d_in[0];
  const int* er=(const int*)d_in[1];
  const int* ea=(const int*)d_in[2];
  const int* et=(const int*)d_in[3];
  const float* mw=(const float*)d_in[4];
  const float* mb=(const float*)d_in[5];
  const float* w1=(const float*)d_in[6];
  const float* root1=(const float*)d_in[7];
  const float* b1=(const float*)d_in[8];
  const float* w2=(const float*)d_in[9];
  const float* root2=(const float*)d_in[10];
  const float* b2=(const float*)d_in[11];
  const float* clsw=(const float*)d_in[12];
  const float* clsb=(const float*)d_in[13];
  float* out=(float*)d_out;
  char* w=(char*)d_ws; size_t ofs=0;
  auto alloc=[&](size_t bytes){void* p=w+ofs;ofs=(ofs+bytes+255)&~(size_t)255;return p;};
  unsigned* cnt=(unsigned*)alloc(NBINS*4);
  unsigned* off=(unsigned*)alloc(NBINS*4);
  unsigned* cur=(unsigned*)alloc(NBINS*4);
  float* invc=(float*)alloc(NBINS*4);
  unsigned* aux=(unsigned*)alloc(1024*4);
  int* srcbuf=(int*)alloc((size_t)2*NE*4);
  u16* hrepb=(u16*)alloc((size_t)NR*HD*2);
  u16* h1repb=(u16*)alloc((size_t)NR*HD*2);
  float* c1=(float*)alloc(HD*4);
  u16* packb=(u16*)alloc((size_t)576*512*2);
  u16* h1ub=(u16*)alloc((size_t)NU*HD*2);
  u16* mbuf=(u16*)alloc((size_t)NR*1152*2);
  u16* y1b=mbuf;
  hipMemsetAsync(cnt,0,NBINS*4,stream);
  k_mlp<<<(NR*HD+255)/256,256,0,stream>>>(x,mw,mb,hrepb);
  k_c1<<<1,128,0,stream>>>(mb,root1,b1,c1);
  k_pack<<<(576*512+255)/256,256,0,stream>>>(w1,root1,w2,root2,packb);
  k_hist<<<(NE+255)/256,256,0,stream>>>(er,ea,et,cnt);
  k_scan1<<<NSCAN,256,0,stream>>>(cnt,off,aux);
  k_scan2<<<1,1024,0,stream>>>(aux);
  k_scan3<<<(NBINS+255)/256,256,0,stream>>>(off,aux,cur,cnt,invc);
  k_scatter<<<(NE+255)/256,256,0,stream>>>(er,ea,et,cur,srcbuf);
  // Y1 = hrep @ [W1_r]  (bf16 MFMA, 8 panels via grid.y)
  k_mgemm<4,0><<<dim3((NR+31)/32,8),256,0,stream>>>(hrepb,packb,0,nullptr,y1b,nullptr,nullptr,NR,HD,1024);
  // h1rep = relu(hrep @ root1 + b1)
  k_mgemm<4,0><<<dim3((NR+31)/32,1),256,0,stream>>>(hrepb,packb,256,b1,h1repb,nullptr,nullptr,NR,HD,HD);
  k_agg1<<<NU/4,256,0,stream>>>(y1b,off,cnt,invc,srcbuf,c1,h1ub);
  k_agg2<<<NR/4,256,0,stream>>>(h1ub,h1repb,off,cnt,invc,srcbuf,mbuf);
  // out = relu(mbuf @ [w2;root2] + b2) @ clsw + clsb
  k_mgemm<36,2><<<dim3((NR+31)/32,1),256,0,stream>>>(mbuf,packb,288,b2,out,clsw,clsb,NR,1152,0);
}